// Round 8
// baseline (309.039 us; speedup 1.0000x reference)
//
#include <hip/hip_runtime.h>
#include <cstdint>
#include <cstddef>

// Problem constants
constexpr int Bc = 4;
constexpr int Tc = 4096;
constexpr int Cc = 1024;
constexpr int Hc = 16;
constexpr int Dc = 64;
constexpr int Mc = Bc * Tc;        // 16384 rows
constexpr int N1c = 3 * Cc;        // 3072
constexpr int Kc = Cc;             // 1024
constexpr int KBc = Kc / 32;       // 32 k-tiles

typedef __bf16 bf16x8 __attribute__((ext_vector_type(8)));
typedef float  f32x4  __attribute__((ext_vector_type(4)));
typedef __attribute__((address_space(1))) uint32_t gu32;
typedef __attribute__((address_space(3))) uint32_t lu32;

__device__ __forceinline__ float bf2f(unsigned short u) {
    return __uint_as_float(((unsigned)u) << 16);
}
__device__ __forceinline__ unsigned short f2bf(float f) {
    unsigned u = __float_as_uint(f);
    u += 0x7FFF + ((u >> 16) & 1);   // round-to-nearest-even (finite values)
    return (unsigned short)(u >> 16);
}

__device__ __forceinline__ void load_lds16(const void* g, void* l) {
    // wave-uniform LDS base + lane*16; per-lane global address
    __builtin_amdgcn_global_load_lds((gu32*)(uintptr_t)g, (lu32*)(uintptr_t)l, 16, 0, 0);
}

// ============ packed-fragment layout ============
// A 16(rows)x32(k) tile = 512 bf16 = 64 lanes x 8 elems, contiguous in lane order.
// lane = fq*16 + fr  (fr = row&15, fq = (k&31)>>3), elem j = k&7.
// tile index: (row>>4)*KB + (k>>5). Wave fragment load = tile_base + lane*16B
// -> one coalesced b128 (global) or one conflict-free ds_read_b128 (LDS).

// ---------------- merged prep: convert_x + both weight transposes -------------
// grid = 8192 (convert_x) + 3072 (Wqkv transpose) + 1024 (Wout transpose)
__global__ __launch_bounds__(256) void prep_kernel(
    const float* __restrict__ x,    unsigned short* __restrict__ Ap,
    const float* __restrict__ Wqkv, unsigned short* __restrict__ Wqkp,
    const float* __restrict__ Wout, unsigned short* __restrict__ Wop) {
    __shared__ float tile[32][33];
    const int bid = blockIdx.x;
    const int tid = threadIdx.x;

    if (bid < 8192) {
        // ---- convert_x body (x fp32 [M][K] -> packed bf16 fragments) ----
        const int w = tid >> 6, lane = tid & 63;
        const int t = bid * 4 + w;          // tile id = mb*KB + kb
        const int mb = t >> 5, kb = t & 31;
        const int r = lane >> 2, c = lane & 3;
        const float* src = x + (size_t)(mb * 16 + r) * Kc + kb * 32 + c * 8;
        float4 f0 = *(const float4*)src;
        float4 f1 = *(const float4*)(src + 4);
        unsigned short u[8];
        u[0] = f2bf(f0.x); u[1] = f2bf(f0.y); u[2] = f2bf(f0.z); u[3] = f2bf(f0.w);
        u[4] = f2bf(f1.x); u[5] = f2bf(f1.y); u[6] = f2bf(f1.z); u[7] = f2bf(f1.w);
        *(uint4*)(Ap + (size_t)t * 512 + (c * 16 + r) * 8) = *(uint4*)u;
        return;
    }

    // ---- W fp32 [K][N] -> packed bf16 fragments (transposed) ----
    const float* W; unsigned short* Bp; int N; int b2;
    if (bid < 8192 + 3072) { W = Wqkv; Bp = Wqkp; N = 3072; b2 = bid - 8192; }
    else                   { W = Wout; Bp = Wop;  N = 1024; b2 = bid - 11264; }
    const int NT = N >> 5;
    const int n0 = (b2 % NT) * 32, k0 = (b2 / NT) * 32;
    const int tx = tid & 31, ty = tid >> 5;
    for (int i = ty; i < 32; i += 8)
        tile[i][tx] = W[(size_t)(k0 + i) * N + n0 + tx];
    __syncthreads();
    const int t = tid;
    const int h = t >> 7, rr = t & 127, lane = rr >> 1, half = rr & 1;
    const int fq = lane >> 4, fn = lane & 15;
    unsigned short u[4];
    #pragma unroll
    for (int j = 0; j < 4; ++j)
        u[j] = f2bf(tile[fq * 8 + half * 4 + j][h * 16 + fn]);
    size_t tileIdx = (size_t)((n0 >> 4) + h) * (Kc >> 5) + (k0 >> 5);
    *(uint2*)(Bp + tileIdx * 512 + lane * 8 + half * 4) = *(uint2*)u;
}

// ---------------- LDS-staged bf16 MFMA GEMM, BK=64 (r5 verified, 102 us) -------
// 128x128 block, 4 waves, 64x64/wave, 4 blocks/CU, 32 KB LDS, packed A and B.
// GEMM1 is launched as THREE N-slices of 1024 cols each: grid = 8*128 = 1024
// blocks = EXACTLY one resident wave (no tail, unlike r7's M-halves), so the
// slices are ~36 us and anything slower (attn/GEMM2) surfaces in rocprof top-5.
template <bool OUT_BF16>
__global__ __launch_bounds__(256, 4) void lds_gemm_kernel(
    const unsigned short* __restrict__ Ap,
    const unsigned short* __restrict__ Bp,
    const float* __restrict__ bias,
    void* __restrict__ Cout,
    int M, int N, int K, int NB) {
    __shared__ unsigned short sA[16 * 512];   // [mt*2+s][512]  (s = k-subtile)
    __shared__ unsigned short sB[16 * 512];   // [nt*2+s][512]
    const int KB = K >> 5;                    // 32-wide k-tiles
    const int MB = M >> 7;
    const int id   = blockIdx.x;
    const int xcd  = id & 7;
    const int per  = id >> 3;
    const int MSTR = MB >> 3;
    const int byl  = per & 7;
    const int bx   = (per >> 3) % NB;
    const int pass = per / (8 * NB);
    const int by   = xcd * MSTR + pass * 8 + byl;

    const int w    = threadIdx.x >> 6;
    const int lane = threadIdx.x & 63;
    const int m0 = by * 128;
    const int n0 = bx * 128;
    const int wm = (w >> 1) * 64;
    const int wn = (w & 1) * 64;

    // staging: wave w owns LDS tiles {4w..4w+3} of A and of B.
    // LDS tile t -> (mt = t>>1, s = t&1); global k-tile = 2j + s.
    const unsigned short* gA[4];
    const unsigned short* gB[4];
    unsigned short* lA[4];
    unsigned short* lB[4];
    #pragma unroll
    for (int i = 0; i < 4; ++i) {
        const int t  = w * 4 + i;
        const int mt = t >> 1, s = t & 1;
        gA[i] = Ap + ((size_t)(by * 8 + mt) * KB + s) * 512 + lane * 8;
        gB[i] = Bp + ((size_t)(bx * 8 + mt) * KB + s) * 512 + lane * 8;
        lA[i] = sA + t * 512;
        lB[i] = sB + t * 512;
    }

    // fragment read pointers (linear in lane -> conflict-free ds_read_b128)
    const unsigned short* aP = sA + (wm >> 4) * 2 * 512 + lane * 8;
    const unsigned short* bP = sB + (wn >> 4) * 2 * 512 + lane * 8;

    const f32x4 zero4 = {0.f, 0.f, 0.f, 0.f};
    f32x4 acc[4][4];
    #pragma unroll
    for (int i = 0; i < 4; ++i)
        #pragma unroll
        for (int j = 0; j < 4; ++j) acc[i][j] = zero4;

    const int NIT = K >> 6;   // BK=64 iterations
    #pragma unroll 1
    for (int jt = 0; jt < NIT; ++jt) {
        #pragma unroll
        for (int i = 0; i < 4; ++i) {
            load_lds16(gA[i], lA[i]);
            load_lds16(gB[i], lB[i]);
        }
        #pragma unroll
        for (int i = 0; i < 4; ++i) { gA[i] += 1024; gB[i] += 1024; }
        __syncthreads();   // drains DMA (vmcnt) + aligns waves

        #pragma unroll
        for (int kk = 0; kk < 2; ++kk) {
            bf16x8 af[4], bfr[4];
            #pragma unroll
            for (int mi = 0; mi < 4; ++mi)
                af[mi]  = *(const bf16x8*)(aP + (mi * 2 + kk) * 512);
            #pragma unroll
            for (int ni = 0; ni < 4; ++ni)
                bfr[ni] = *(const bf16x8*)(bP + (ni * 2 + kk) * 512);
            #pragma unroll
            for (int mi = 0; mi < 4; ++mi)
                #pragma unroll
                for (int ni = 0; ni < 4; ++ni)
                    acc[mi][ni] = __builtin_amdgcn_mfma_f32_16x16x32_bf16(
                        af[mi], bfr[ni], acc[mi][ni], 0, 0, 0);
        }
        __syncthreads();   // LDS consumed before next staging overwrites
    }

    // epilogue: D row = (lane>>4)*4 + reg, col = lane&15
    const int fr = lane & 15;
    const int fq = lane >> 4;
    #pragma unroll
    for (int mi = 0; mi < 4; ++mi) {
        #pragma unroll
        for (int ni = 0; ni < 4; ++ni) {
            int row = m0 + wm + mi * 16 + fq * 4;
            int col = n0 + wn + ni * 16 + fr;
            float bb = bias[col];
            #pragma unroll
            for (int r = 0; r < 4; ++r) {
                float v = acc[mi][ni][r] + bb;
                if (OUT_BF16)
                    ((unsigned short*)Cout)[(size_t)(row + r) * N + col] = f2bf(v);
                else
                    ((float*)Cout)[(size_t)(row + r) * N + col] = v;
            }
        }
    }
}

// ---------------- per-token head-axis attention, MFMA, packed-fragment out ----------------
// One wave per token. r0 math path with two data-path fixes:
//  (1) V transposed at LDS-WRITE time into skewed rows:
//      element (g,d) at short-offset d*24 + (d>>3)*8 + g.
//      The (d>>3)*8 skew breaks the 192-short row-group periodicity
//      (192 = 0 mod 32 banks -> 16-way write conflict without it; with it,
//      writes are ~2-way = free). Each PV B-fragment is then ONE 16B-aligned
//      ds_read_b128 of row d (cols g0..g0+7) -- replaces 32 scalar 4-way
//      conflicted ds_read_u16. Semantics identical to r0's gather.
//  (2) o deferred to registers; sVt reused as sO staging (wave-private, zero
//      extra LDS, 8 blocks/CU kept); output written as coalesced b128 packed
//      stores (r2-verified pattern) instead of 16 scattered 2B stores.
__global__ __launch_bounds__(256) void attn_mfma_kernel(
    const unsigned short* __restrict__ qkv,
    unsigned short* __restrict__ attP) {
    // per-token: sVt 1600 shorts (skewed, max 1584) = 3200B | sP [16][20] f32
    __shared__ char smem[4 * 4480];
    const int w    = threadIdx.x >> 6;
    const int lane = threadIdx.x & 63;
    const int m    = lane & 15;
    const int q    = lane >> 4;
    const int row  = blockIdx.x * 4 + w;
    unsigned short* sVt = (unsigned short*)(smem + w * 4480);
    float*          sP  = (float*)(smem + w * 4480 + 3200);

    const unsigned short* src = qkv + (size_t)row * 3072;

    bf16x8 aq0 = *(const bf16x8*)(src + m * 64 + q * 8);
    bf16x8 aq1 = *(const bf16x8*)(src + m * 64 + 32 + q * 8);
    bf16x8 bk0 = *(const bf16x8*)(src + 1024 + m * 64 + q * 8);
    bf16x8 bk1 = *(const bf16x8*)(src + 1024 + m * 64 + 32 + q * 8);

    // V transpose-stage: thread reads V[g][8p..8p+7] (16B), writes 8 scalars
    // to sVt rows d=8p+i: offset = (8p+i)*24 + p*8 + g = 200p + 24i + g.
    #pragma unroll
    for (int t = 0; t < 2; ++t) {
        int G = t * 64 + lane;
        int g = G >> 3, p = G & 7;
        uint4 vv = *(const uint4*)(src + 2048 + G * 8);
        const unsigned short* vs = (const unsigned short*)&vv;
        #pragma unroll
        for (int i = 0; i < 8; ++i)
            sVt[200 * p + 24 * i + g] = vs[i];
    }

    f32x4 s = {0.f, 0.f, 0.f, 0.f};
    s = __builtin_amdgcn_mfma_f32_16x16x32_bf16(aq0, bk0, s, 0, 0, 0);
    s = __builtin_amdgcn_mfma_f32_16x16x32_bf16(aq1, bk1, s, 0, 0, 0);

    #pragma unroll
    for (int r = 0; r < 4; ++r) {
        float t0 = s[r] * 0.125f;
        float mx = t0;
        mx = fmaxf(mx, __shfl_xor(mx, 1));
        mx = fmaxf(mx, __shfl_xor(mx, 2));
        mx = fmaxf(mx, __shfl_xor(mx, 4));
        mx = fmaxf(mx, __shfl_xor(mx, 8));
        float e = __expf(t0 - mx);
        float su = e;
        su += __shfl_xor(su, 1);
        su += __shfl_xor(su, 2);
        su += __shfl_xor(su, 4);
        su += __shfl_xor(su, 8);
        sP[(q * 4 + r) * 20 + m] = e / su;
    }
    __syncthreads();   // sVt + sP visible (wave-private; barrier also aligns)

    const float* pr = sP + m * 20 + (q & 1) * 8;
    float4 pf0 = *(const float4*)(pr);
    float4 pf1 = *(const float4*)(pr + 4);
    const bool act = (q < 2);
    union { unsigned short u[8]; bf16x8 b; } pa;
    pa.u[0] = act ? f2bf(pf0.x) : 0;
    pa.u[1] = act ? f2bf(pf0.y) : 0;
    pa.u[2] = act ? f2bf(pf0.z) : 0;
    pa.u[3] = act ? f2bf(pf0.w) : 0;
    pa.u[4] = act ? f2bf(pf1.x) : 0;
    pa.u[5] = act ? f2bf(pf1.y) : 0;
    pa.u[6] = act ? f2bf(pf1.z) : 0;
    pa.u[7] = act ? f2bf(pf1.w) : 0;

    // PV: B-fragment elem j of lane (m,q) = V[(q&1)*8+j][d], d = c4*16+m
    //   = sVt row d, cols (q&1)*8 .. +7  -> one aligned ds_read_b128
    float o4[4][4];
    #pragma unroll
    for (int c4 = 0; c4 < 4; ++c4) {
        const int d = c4 * 16 + m;
        bf16x8 vf = *(const bf16x8*)(sVt + d * 24 + (d >> 3) * 8 + (q & 1) * 8);
        f32x4 o = {0.f, 0.f, 0.f, 0.f};
        o = __builtin_amdgcn_mfma_f32_16x16x32_bf16(pa.b, vf, o, 0, 0, 0);
        #pragma unroll
        for (int r = 0; r < 4; ++r) o4[c4][r] = o[r];
    }
    __syncthreads();   // all sVt reads retired before reuse as sO

    // stage output in sVt-as-sO (r2-verified padded layout: +8 shorts per 64)
    unsigned short* sO = sVt;
    #pragma unroll
    for (int c4 = 0; c4 < 4; ++c4) {
        #pragma unroll
        for (int r = 0; r < 4; ++r) {
            int col = (q * 4 + r) * 64 + c4 * 16 + m;   // k index in [0,1024)
            sO[col + ((col >> 6) << 3)] = f2bf(o4[c4][r]);
        }
    }
    __syncthreads();   // sO writes retired before cross-lane reads

    // packed-fragment write-out: 2 x dwordx4 per lane, 16B-aligned (r2 pattern)
    const size_t tileBase = (size_t)(row >> 4) * 32 * 512;   // token's m-block (KB=32)
    const int fr_tok = row & 15;
    #pragma unroll
    for (int t = 0; t < 2; ++t) {
        int j = t * 64 + lane;                               // col group j*8..j*8+7
        uint4 val = *(const uint4*)(sO + j * 8 + ((j >> 3) << 3));
        *(uint4*)(attP + tileBase + (size_t)(j >> 2) * 512
                  + ((j & 3) * 16 + fr_tok) * 8) = val;
    }
}

extern "C" void kernel_launch(void* const* d_in, const int* in_sizes, int n_in,
                              void* d_out, int out_size, void* d_ws, size_t ws_size,
                              hipStream_t stream) {
    const float* x    = (const float*)d_in[0];
    const float* Wqkv = (const float*)d_in[1];
    const float* bqkv = (const float*)d_in[2];
    const float* Wout = (const float*)d_in[3];
    const float* bout = (const float*)d_in[4];
    float* out = (float*)d_out;

    // workspace: xp 32M | Wqkv_p 6M | Wout_p 2M | qkv 96M = ~136 MB
    char* ws = (char*)d_ws;
    unsigned short* xp   = (unsigned short*)ws;                 ws += (size_t)Mc * Kc * 2;
    unsigned short* Wqkp = (unsigned short*)ws;                 ws += (size_t)N1c * Kc * 2;
    unsigned short* Wop  = (unsigned short*)ws;                 ws += (size_t)Cc * Kc * 2;
    unsigned short* qkv  = (unsigned short*)ws;
    unsigned short* attP = xp;   // alias: xp dead after GEMM1 (packed [M/16][32] tiles)

    // 1) prep: x -> packed fragments; weights -> packed fragments (transposed)
    prep_kernel<<<8192 + 3072 + 1024, 256, 0, stream>>>(x, xp, Wqkv, Wqkp, Wout, Wop);

    // 2) qkv = x @ W_qkv + b_qkv — THREE N-slices of 1024 cols, each an exact
    //    1024-block resident wave (instrumentation + no-tail split).
    for (int p = 0; p < 3; ++p) {
        const unsigned short* Bp_p = Wqkp + (size_t)p * 64 * KBc * 512;  // 64 n-tiles/slice
        lds_gemm_kernel<true><<<8 * (Mc / 128), 256, 0, stream>>>(
            xp, Bp_p, bqkv + p * 1024, qkv + p * 1024, Mc, N1c, Kc, 8);
    }

    // 3) head-axis attention per token (MFMA), writes packed-fragment A
    attn_mfma_kernel<<<Mc / 4, 256, 0, stream>>>(qkv, attP);

    // 4) out = att @ W_out + b_out (fp32 row-major out)
    lds_gemm_kernel<false><<<(Cc / 128) * (Mc / 128), 256, 0, stream>>>(
        attP, Wop, bout, out, Mc, Cc, Kc, Cc / 128);
}

// Round 9
// 287.465 us; speedup vs baseline: 1.0750x; 1.0750x over previous
//
#include <hip/hip_runtime.h>
#include <hip/hip_cooperative_groups.h>
#include <cstdint>
#include <cstddef>

namespace cg = cooperative_groups;

// Problem constants
constexpr int Bc = 4;
constexpr int Tc = 4096;
constexpr int Cc = 1024;
constexpr int Hc = 16;
constexpr int Dc = 64;
constexpr int Mc = Bc * Tc;        // 16384 rows
constexpr int N1c = 3 * Cc;        // 3072
constexpr int Kc = Cc;             // 1024
constexpr int KBc = Kc / 32;       // 32 k-tiles

typedef __bf16 bf16x8 __attribute__((ext_vector_type(8)));
typedef float  f32x4  __attribute__((ext_vector_type(4)));
typedef __attribute__((address_space(1))) uint32_t gu32;
typedef __attribute__((address_space(3))) uint32_t lu32;

__device__ __forceinline__ unsigned short f2bf(float f) {
    unsigned u = __float_as_uint(f);
    u += 0x7FFF + ((u >> 16) & 1);   // round-to-nearest-even (finite values)
    return (unsigned short)(u >> 16);
}

__device__ __forceinline__ void load_lds16(const void* g, void* l) {
    // wave-uniform LDS base + lane*16; per-lane global address
    __builtin_amdgcn_global_load_lds((gu32*)(uintptr_t)g, (lu32*)(uintptr_t)l, 16, 0, 0);
}

// ============ packed-fragment layout ============
// A 16(rows)x32(k) tile = 512 bf16 = 64 lanes x 8 elems, contiguous in lane order.
// lane = fq*16 + fr (fr=row&15, fq=(k&31)>>3), elem j = k&7.
// tile index: (row>>4)*KB + (k>>5).

// ---------------- prep body: convert_x + weight transposes --------------------
// virtual block t in [0, 12288): 8192 convert_x | 3072 Wqkv | 1024 Wout
__device__ __forceinline__ void prep_body(
    int bid, int tid,
    const float* __restrict__ x,    unsigned short* __restrict__ Ap,
    const float* __restrict__ Wqkv, unsigned short* __restrict__ Wqkp,
    const float* __restrict__ Wout, unsigned short* __restrict__ Wop,
    char* smemc) {
    if (bid < 8192) {
        // ---- convert_x (x fp32 [M][K] -> packed bf16 fragments), no LDS ----
        const int w = tid >> 6, lane = tid & 63;
        const int t = bid * 4 + w;          // tile id = mb*KB + kb
        const int mb = t >> 5, kb = t & 31;
        const int r = lane >> 2, c = lane & 3;
        const float* src = x + (size_t)(mb * 16 + r) * Kc + kb * 32 + c * 8;
        float4 f0 = *(const float4*)src;
        float4 f1 = *(const float4*)(src + 4);
        unsigned short u[8];
        u[0] = f2bf(f0.x); u[1] = f2bf(f0.y); u[2] = f2bf(f0.z); u[3] = f2bf(f0.w);
        u[4] = f2bf(f1.x); u[5] = f2bf(f1.y); u[6] = f2bf(f1.z); u[7] = f2bf(f1.w);
        *(uint4*)(Ap + (size_t)t * 512 + (c * 16 + r) * 8) = *(uint4*)u;
        return;
    }
    // ---- W fp32 [K][N] -> packed bf16 fragments (transposed) ----
    float (*tile)[33] = (float(*)[33])smemc;
    const float* W; unsigned short* Bp; int N; int b2;
    if (bid < 8192 + 3072) { W = Wqkv; Bp = Wqkp; N = 3072; b2 = bid - 8192; }
    else                   { W = Wout; Bp = Wop;  N = 1024; b2 = bid - 11264; }
    __syncthreads();   // protect LDS tile reuse across grid-stride iterations
    const int NT = N >> 5;
    const int n0 = (b2 % NT) * 32, k0 = (b2 / NT) * 32;
    const int tx = tid & 31, ty = tid >> 5;
    for (int i = ty; i < 32; i += 8)
        tile[i][tx] = W[(size_t)(k0 + i) * N + n0 + tx];
    __syncthreads();
    const int t = tid;
    const int h = t >> 7, rr = t & 127, lane = rr >> 1, half = rr & 1;
    const int fq = lane >> 4, fn = lane & 15;
    unsigned short u[4];
    #pragma unroll
    for (int j = 0; j < 4; ++j)
        u[j] = f2bf(tile[fq * 8 + half * 4 + j][h * 16 + fn]);
    size_t tileIdx = (size_t)((n0 >> 4) + h) * (Kc >> 5) + (k0 >> 5);
    *(uint2*)(Bp + tileIdx * 512 + lane * 8 + half * 4) = *(uint2*)u;
}

// ---------------- GEMM tile body: BK=64, 128x128, 4 waves (r5-verified) -------
template <bool OUT_BF16>
__device__ __forceinline__ void gemm_body(
    int id, int tid,
    const unsigned short* __restrict__ Ap,
    const unsigned short* __restrict__ Bp,
    const float* __restrict__ bias,
    void* __restrict__ Cout,
    int M, int N, int K, int NB, char* smemc) {
    unsigned short* sA = (unsigned short*)smemc;          // 16*512 shorts
    unsigned short* sB = sA + 16 * 512;                   // 16*512 shorts
    const int KB = K >> 5;
    const int xcd  = id & 7;
    const int per  = id >> 3;
    const int byl  = per & 7;
    const int bx   = (per >> 3) % NB;
    const int pass = per / (8 * NB);
    const int by   = xcd * ((M >> 7) >> 3) + pass * 8 + byl;

    const int w    = tid >> 6;
    const int lane = tid & 63;
    const int m0 = by * 128;
    const int n0 = bx * 128;
    const int wm = (w >> 1) * 64;
    const int wn = (w & 1) * 64;

    const unsigned short* gA[4];
    const unsigned short* gB[4];
    unsigned short* lA[4];
    unsigned short* lB[4];
    #pragma unroll
    for (int i = 0; i < 4; ++i) {
        const int t  = w * 4 + i;
        const int mt = t >> 1, s = t & 1;
        gA[i] = Ap + ((size_t)(by * 8 + mt) * KB + s) * 512 + lane * 8;
        gB[i] = Bp + ((size_t)(bx * 8 + mt) * KB + s) * 512 + lane * 8;
        lA[i] = sA + t * 512;
        lB[i] = sB + t * 512;
    }

    const unsigned short* aP = sA + (wm >> 4) * 2 * 512 + lane * 8;
    const unsigned short* bP = sB + (wn >> 4) * 2 * 512 + lane * 8;

    const f32x4 zero4 = {0.f, 0.f, 0.f, 0.f};
    f32x4 acc[4][4];
    #pragma unroll
    for (int i = 0; i < 4; ++i)
        #pragma unroll
        for (int j = 0; j < 4; ++j) acc[i][j] = zero4;

    const int NIT = K >> 6;   // BK=64 iterations
    #pragma unroll 1
    for (int jt = 0; jt < NIT; ++jt) {
        #pragma unroll
        for (int i = 0; i < 4; ++i) {
            load_lds16(gA[i], lA[i]);
            load_lds16(gB[i], lB[i]);
        }
        #pragma unroll
        for (int i = 0; i < 4; ++i) { gA[i] += 1024; gB[i] += 1024; }
        __syncthreads();   // drains DMA (vmcnt) + aligns waves

        #pragma unroll
        for (int kk = 0; kk < 2; ++kk) {
            bf16x8 af[4], bfr[4];
            #pragma unroll
            for (int mi = 0; mi < 4; ++mi)
                af[mi]  = *(const bf16x8*)(aP + (mi * 2 + kk) * 512);
            #pragma unroll
            for (int ni = 0; ni < 4; ++ni)
                bfr[ni] = *(const bf16x8*)(bP + (ni * 2 + kk) * 512);
            #pragma unroll
            for (int mi = 0; mi < 4; ++mi)
                #pragma unroll
                for (int ni = 0; ni < 4; ++ni)
                    acc[mi][ni] = __builtin_amdgcn_mfma_f32_16x16x32_bf16(
                        af[mi], bfr[ni], acc[mi][ni], 0, 0, 0);
        }
        __syncthreads();   // LDS consumed before next staging overwrites
    }

    const int fr = lane & 15;
    const int fq = lane >> 4;
    #pragma unroll
    for (int mi = 0; mi < 4; ++mi) {
        #pragma unroll
        for (int ni = 0; ni < 4; ++ni) {
            int row = m0 + wm + mi * 16 + fq * 4;
            int col = n0 + wn + ni * 16 + fr;
            float bb = bias[col];
            #pragma unroll
            for (int r = 0; r < 4; ++r) {
                float v = acc[mi][ni][r] + bb;
                if (OUT_BF16)
                    ((unsigned short*)Cout)[(size_t)(row + r) * N + col] = f2bf(v);
                else
                    ((float*)Cout)[(size_t)(row + r) * N + col] = v;
            }
        }
    }
}

// ---------------- attention body (r8-verified): virtual block vb -> 4 tokens --
__device__ __forceinline__ void attn_body(
    int vb, int tid,
    const unsigned short* __restrict__ qkv,
    unsigned short* __restrict__ attP, char* smemc) {
    const int w    = tid >> 6;
    const int lane = tid & 63;
    const int m    = lane & 15;
    const int q    = lane >> 4;
    const int row  = vb * 4 + w;
    unsigned short* sVt = (unsigned short*)(smemc + w * 4480);
    float*          sP  = (float*)(smemc + w * 4480 + 3200);

    const unsigned short* src = qkv + (size_t)row * 3072;

    bf16x8 aq0 = *(const bf16x8*)(src + m * 64 + q * 8);
    bf16x8 aq1 = *(const bf16x8*)(src + m * 64 + 32 + q * 8);
    bf16x8 bk0 = *(const bf16x8*)(src + 1024 + m * 64 + q * 8);
    bf16x8 bk1 = *(const bf16x8*)(src + 1024 + m * 64 + 32 + q * 8);

    // V transpose-stage: element (g,d) at short-offset d*24 + (d>>3)*8 + g
    #pragma unroll
    for (int t = 0; t < 2; ++t) {
        int G = t * 64 + lane;
        int g = G >> 3, p = G & 7;
        uint4 vv = *(const uint4*)(src + 2048 + G * 8);
        const unsigned short* vs = (const unsigned short*)&vv;
        #pragma unroll
        for (int i = 0; i < 8; ++i)
            sVt[200 * p + 24 * i + g] = vs[i];
    }

    f32x4 s = {0.f, 0.f, 0.f, 0.f};
    s = __builtin_amdgcn_mfma_f32_16x16x32_bf16(aq0, bk0, s, 0, 0, 0);
    s = __builtin_amdgcn_mfma_f32_16x16x32_bf16(aq1, bk1, s, 0, 0, 0);

    #pragma unroll
    for (int r = 0; r < 4; ++r) {
        float t0 = s[r] * 0.125f;
        float mx = t0;
        mx = fmaxf(mx, __shfl_xor(mx, 1));
        mx = fmaxf(mx, __shfl_xor(mx, 2));
        mx = fmaxf(mx, __shfl_xor(mx, 4));
        mx = fmaxf(mx, __shfl_xor(mx, 8));
        float e = __expf(t0 - mx);
        float su = e;
        su += __shfl_xor(su, 1);
        su += __shfl_xor(su, 2);
        su += __shfl_xor(su, 4);
        su += __shfl_xor(su, 8);
        sP[(q * 4 + r) * 20 + m] = e / su;
    }
    __syncthreads();

    const float* pr = sP + m * 20 + (q & 1) * 8;
    float4 pf0 = *(const float4*)(pr);
    float4 pf1 = *(const float4*)(pr + 4);
    const bool act = (q < 2);
    union { unsigned short u[8]; bf16x8 b; } pa;
    pa.u[0] = act ? f2bf(pf0.x) : 0;
    pa.u[1] = act ? f2bf(pf0.y) : 0;
    pa.u[2] = act ? f2bf(pf0.z) : 0;
    pa.u[3] = act ? f2bf(pf0.w) : 0;
    pa.u[4] = act ? f2bf(pf1.x) : 0;
    pa.u[5] = act ? f2bf(pf1.y) : 0;
    pa.u[6] = act ? f2bf(pf1.z) : 0;
    pa.u[7] = act ? f2bf(pf1.w) : 0;

    // PV: one aligned ds_read_b128 per fragment from skewed sVt
    float o4[4][4];
    #pragma unroll
    for (int c4 = 0; c4 < 4; ++c4) {
        const int d = c4 * 16 + m;
        bf16x8 vf = *(const bf16x8*)(sVt + d * 24 + (d >> 3) * 8 + (q & 1) * 8);
        f32x4 o = {0.f, 0.f, 0.f, 0.f};
        o = __builtin_amdgcn_mfma_f32_16x16x32_bf16(pa.b, vf, o, 0, 0, 0);
        #pragma unroll
        for (int r = 0; r < 4; ++r) o4[c4][r] = o[r];
    }
    __syncthreads();   // all sVt reads retired before reuse as sO

    unsigned short* sO = sVt;
    #pragma unroll
    for (int c4 = 0; c4 < 4; ++c4) {
        #pragma unroll
        for (int r = 0; r < 4; ++r) {
            int col = (q * 4 + r) * 64 + c4 * 16 + m;
            sO[col + ((col >> 6) << 3)] = f2bf(o4[c4][r]);
        }
    }
    __syncthreads();   // sO writes retired before cross-lane reads

    const size_t tileBase = (size_t)(row >> 4) * 32 * 512;
    const int fr_tok = row & 15;
    #pragma unroll
    for (int t = 0; t < 2; ++t) {
        int j = t * 64 + lane;
        uint4 val = *(const uint4*)(sO + j * 8 + ((j >> 3) << 3));
        *(uint4*)(attP + tileBase + (size_t)(j >> 2) * 512
                  + ((j & 3) * 16 + fr_tok) * 8) = val;
    }
}

// ---------------- cooperative megakernel: all 4 stages, 1 dispatch ------------
// 1024 blocks x 256 threads = 4 blocks/CU x 256 CU (co-resident: 32 KB LDS,
// VGPR capped by launch_bounds). Grid-stride counts divide exactly -> uniform
// control flow, in-phase __syncthreads legal. grid.sync() provides the
// device-scope fence needed across XCDs (guide §6 G16).
__global__ __launch_bounds__(256, 4) void mega_kernel(
    const float* __restrict__ x,    unsigned short* __restrict__ xp,
    const float* __restrict__ Wqkv, unsigned short* __restrict__ Wqkp,
    const float* __restrict__ Wout, unsigned short* __restrict__ Wop,
    const float* __restrict__ bqkv, unsigned short* __restrict__ qkv,
    const float* __restrict__ bout, float* __restrict__ out) {
    __shared__ __align__(16) char smem[32768];
    cg::grid_group grid = cg::this_grid();
    const int bid = blockIdx.x, tid = threadIdx.x;

    // phase 1: prep (12 iterations)
    for (int t = bid; t < 12288; t += 1024)
        prep_body(t, tid, x, xp, Wqkv, Wqkp, Wout, Wop, smem);
    grid.sync();
    // phase 2: GEMM1 qkv = x@Wqkv + b (3072 tiles, 3 per block)
    for (int t = bid; t < 3072; t += 1024)
        gemm_body<true>(t, tid, xp, Wqkp, bqkv, qkv, Mc, N1c, Kc, N1c / 128, smem);
    grid.sync();
    // phase 3: attention (4096 virtual blocks, 4 per block); attP aliases xp
    for (int t = bid; t < 4096; t += 1024)
        attn_body(t, tid, qkv, xp, smem);
    grid.sync();
    // phase 4: GEMM2 out = att@Wout + b (1024 tiles, exactly 1 per block)
    gemm_body<false>(bid, tid, xp, Wop, bout, out, Mc, Cc, Kc, Cc / 128, smem);
}

// ---------------- fallback shells (known-good 4-kernel chain) -----------------
__global__ __launch_bounds__(256) void prep_kernel(
    const float* __restrict__ x,    unsigned short* __restrict__ Ap,
    const float* __restrict__ Wqkv, unsigned short* __restrict__ Wqkp,
    const float* __restrict__ Wout, unsigned short* __restrict__ Wop) {
    __shared__ __align__(16) char smem[4224];
    prep_body(blockIdx.x, threadIdx.x, x, Ap, Wqkv, Wqkp, Wout, Wop, smem);
}

template <bool OUT_BF16>
__global__ __launch_bounds__(256, 4) void lds_gemm_kernel(
    const unsigned short* __restrict__ Ap,
    const unsigned short* __restrict__ Bp,
    const float* __restrict__ bias,
    void* __restrict__ Cout,
    int M, int N, int K, int NB) {
    __shared__ __align__(16) char smem[32768];
    gemm_body<OUT_BF16>(blockIdx.x, threadIdx.x, Ap, Bp, bias, Cout, M, N, K, NB, smem);
}

__global__ __launch_bounds__(256) void attn_mfma_kernel(
    const unsigned short* __restrict__ qkv,
    unsigned short* __restrict__ attP) {
    __shared__ __align__(16) char smem[17920];
    attn_body(blockIdx.x, threadIdx.x, qkv, attP, smem);
}

extern "C" void kernel_launch(void* const* d_in, const int* in_sizes, int n_in,
                              void* d_out, int out_size, void* d_ws, size_t ws_size,
                              hipStream_t stream) {
    const float* x    = (const float*)d_in[0];
    const float* Wqkv = (const float*)d_in[1];
    const float* bqkv = (const float*)d_in[2];
    const float* Wout = (const float*)d_in[3];
    const float* bout = (const float*)d_in[4];
    float* out = (float*)d_out;

    // workspace: xp 32M | Wqkv_p 6M | Wout_p 2M | qkv 96M = ~136 MB
    char* ws = (char*)d_ws;
    unsigned short* xp   = (unsigned short*)ws;                 ws += (size_t)Mc * Kc * 2;
    unsigned short* Wqkp = (unsigned short*)ws;                 ws += (size_t)N1c * Kc * 2;
    unsigned short* Wop  = (unsigned short*)ws;                 ws += (size_t)Cc * Kc * 2;
    unsigned short* qkv  = (unsigned short*)ws;

    static int coop_ok = -1;   // -1 untried | 1 works | 0 fall back
    if (coop_ok != 0) {
        void* args[] = {
            (void*)&x,    (void*)&xp,
            (void*)&Wqkv, (void*)&Wqkp,
            (void*)&Wout, (void*)&Wop,
            (void*)&bqkv, (void*)&qkv,
            (void*)&bout, (void*)&out,
        };
        hipError_t e = hipLaunchCooperativeKernel(
            reinterpret_cast<const void*>(mega_kernel),
            dim3(1024), dim3(256), args, 0, stream);
        if (e == hipSuccess) { coop_ok = 1; return; }
        (void)hipGetLastError();   // clear sticky error, use fallback chain
        coop_ok = 0;
    }

    // fallback: verified 4-kernel chain (r5-equivalent)
    prep_kernel<<<8192 + 3072 + 1024, 256, 0, stream>>>(x, xp, Wqkv, Wqkp, Wout, Wop);
    lds_gemm_kernel<true><<<(N1c / 128) * (Mc / 128), 256, 0, stream>>>(
        xp, Wqkp, bqkv, qkv, Mc, N1c, Kc, N1c / 128);
    attn_mfma_kernel<<<Mc / 4, 256, 0, stream>>>(qkv, xp);
    lds_gemm_kernel<false><<<(Cc / 128) * (Mc / 128), 256, 0, stream>>>(
        xp, Wop, bout, out, Mc, Cc, Kc, Cc / 128);
}